// Round 7
// baseline (369.699 us; speedup 1.0000x reference)
//
#include <hip/hip_runtime.h>
#include <math.h>

#define HID  50
#define TT   512
#define BT   8       // REAL batches per block (MFMA N=16; cols 8..15 phantom)
#define BROW 16      // LDS H-plane rows (MFMA N)
#define NCW  13      // compute waves, one 16-row M-tile each; wave 13 = chore
#define NTH  896     // 14 waves
#define HS   72      // H plane row stride in shorts (144 B, 16B-aligned)
#define L2E 1.44269504088896f
#define K2C 2.88539008177793f   // 2*log2(e)

typedef __attribute__((ext_vector_type(8))) short bf16x8;
typedef __attribute__((ext_vector_type(4))) float f32x4;

__device__ __forceinline__ unsigned short bf16_rtne(float f) {
    unsigned u = __float_as_uint(f);
    u = (u + 0x7FFFu + ((u >> 16) & 1u)) >> 16;
    return (unsigned short)u;
}
__device__ __forceinline__ float bf16_f32(unsigned short s) {
    return __uint_as_float(((unsigned)s) << 16);
}

// R19 = R16 resubmit #3 (infra: 2x acquisition timeout + 1x container
// failure — kernel has never actually run; R14 precedent shows
// "container failed twice" is infra, its resubmit ran fine).
// R16 = R13 structure (plain __syncthreads, p-indexed buffers — the proven
// 221 µs kernel; R15's lgkm-only barrier + sched_barrier REGRESSED and is
// reverted) with ONE change: BT 16->8, grid 256->512 => TWO blocks per CU.
//
// Theory: the recurrence is latency-chain-bound (per-step span ~1040 cy vs
// ~330 cy modeled chain; VALUBusy only 50%, occupancy 39% = 1 block/CU).
// A second independent block per CU interleaves its dependent chain with
// the first block's barrier/latency holes. Resources fit: 28/32 waves,
// 2x4.6 KB LDS, VGPR 20.
// MFMA cols 8..15 are phantom: their H rows are zeroed and never receive
// x/bias slot markers, so gates=0 -> Ei..Eo=1 -> cs=0 -> h=0 forever;
// phantom columns never affect real ones (independent dot products) and
// their y is never stored.
//
// Math (A rows pre-scaled by log2e for i,f,o / 2*log2e for g):
//   Ei=2^-i', Ef=2^-f', Eg=2^g', Eo=2^-o'
//   cs = [cs*(1+Ei)(1+Eg) + K2*(Eg-1)*(1+Ef)] * rcp((1+Ef)(1+Ei)(1+Eg))
//   Ec = 2^cs;  h = (Ec-1) * rcp((1+Eo)(1+Ec))
// K-slots: 0..49 = s*W_hh | 50 = (s*Wih)_hi (x_hi) | 51 = (s*bias)_hi (1.0)
//          52 = (s*Wih)_hi (x_lo) | 53 = (s*bias)_lo (1.0) | 54 = (s*Wih)_lo (x_hi)
__global__ __launch_bounds__(NTH, 1) void lstm_mfma12_kernel(
    const float* __restrict__ x,      // [B, T]
    const float* __restrict__ W_ih,   // [200, 1]
    const float* __restrict__ W_hh,   // [200, 50]
    const float* __restrict__ b_ih,   // [200]
    const float* __restrict__ b_hh,   // [200]
    const float* __restrict__ W_out,  // [1, 50]
    const float* __restrict__ b_out,  // [1]
    float* __restrict__ out)          // [B, T]
{
    const int tid  = threadIdx.x;
    const int lane = tid & 63;
    const int wv   = tid >> 6;       // 0..13
    const int col  = lane & 15;      // A-m / B-n(batch) / D-col(batch)
    const int quad = lane >> 4;      // k-octet / D row-group

    __shared__ __align__(16) unsigned short Hh[2][BROW][HS];

    // zero both H buffers (phantom rows 8..15 + k-slots 55..63 + pads stay 0)
    for (int i = tid; i < 2 * BROW * HS; i += NTH)
        (&Hh[0][0][0])[i] = 0;

    // persistent A fragments (single plane, PRE-SCALED rows)
    bf16x8 Ah[2];
    float cs = 0.f;                            // 2*log2e * c
    const int uo = wv * 4 + quad;              // output unit of this lane

    if (wv < NCW) {
        const int gh  = wv * 16 + col;          // g^ row
        const int u   = gh >> 2;
        const int ty  = gh & 3;
        const bool vl = (u < HID);
        const int og  = ty * HID + u;           // original gate row
        const float sc = (ty == 2) ? K2C : L2E;
        #pragma unroll
        for (int kk = 0; kk < 2; ++kk) {
            #pragma unroll
            for (int j = 0; j < 8; ++j) {
                const int k = kk * 32 + quad * 8 + j;
                float v = 0.f;
                if (vl) {
                    if (k < HID)      v = sc * W_hh[og * HID + k];
                    else if (k == 50) v = sc * W_ih[og];
                    else if (k == 51) v = sc * (b_ih[og] + b_hh[og]);
                    else if (k == 52) v = sc * W_ih[og];
                    else if (k == 53) {
                        const float sb = sc * (b_ih[og] + b_hh[og]);
                        v = sb - bf16_f32(bf16_rtne(sb));
                    } else if (k == 54) {
                        const float sw = sc * W_ih[og];
                        v = sw - bf16_f32(bf16_rtne(sw));
                    }
                }
                Ah[kk][j] = (short)bf16_rtne(v);
            }
        }
    } else {
        // chore wave: A row0 = hi(W_out), row1 = W_out - hi(W_out)
        #pragma unroll
        for (int kk = 0; kk < 2; ++kk) {
            #pragma unroll
            for (int j = 0; j < 8; ++j) {
                const int k = kk * 32 + quad * 8 + j;
                const float v = (k < HID) ? W_out[k] : 0.f;
                const unsigned short hi = bf16_rtne(v);
                short val = 0;
                if (col == 0)      val = (short)hi;
                else if (col == 1) val = (short)bf16_rtne(v - bf16_f32(hi));
                Ah[kk][j] = val;
            }
        }
    }
    const float bo = b_out[0];
    float* yout = out + (size_t)blockIdx.x * BT * TT;

    // chore-wave x pipeline state (lanes 16..23 own batch b = lane-16)
    const int xb = (lane >= 16 && lane < 16 + BT) ? (lane - 16) : 0;
    const float* xrow = x + (size_t)(blockIdx.x * BT + xb) * TT;
    float xa = 0.f;
    if (wv == NCW && lane >= 16 && lane < 16 + BT)
        xa = xrow[1];                            // x[b][1] for step t=0's write

    __syncthreads();    // zeroed H visible

    // buffer-0 slots for t=0: x_0 hi/lo + bias-1.0 markers (packed b32 writes)
    if (tid < BT) {
        const float x0 = x[(size_t)(blockIdx.x * BT + tid) * TT];
        const unsigned short hx = bf16_rtne(x0);
        const unsigned short lx = bf16_rtne(x0 - bf16_f32(hx));
        unsigned* row32 = (unsigned*)&Hh[0][tid][0];
        row32[25] = (unsigned)hx | (0x3F80u << 16);   // k=50,51
        row32[26] = (unsigned)lx | (0x3F80u << 16);   // k=52,53
        Hh[0][tid][54] = hx;                          // k=54
    }
    __syncthreads();

    for (int t = 0; t < TT; ++t) {
        const int p = t & 1;        // read buffer; write 1-p

        if (wv < NCW) {
            // ---- compute wave: one tile ----
            const unsigned short* hrow = &Hh[p][col][0];
            const bf16x8 B0 = *(const bf16x8*)&hrow[quad * 8];
            const bf16x8 B1 = *(const bf16x8*)&hrow[32 + quad * 8];

            const f32x4 z = {0.f, 0.f, 0.f, 0.f};
            f32x4 a0 = __builtin_amdgcn_mfma_f32_16x16x32_bf16(Ah[0], B0, z, 0, 0, 0);
            f32x4 a1 = __builtin_amdgcn_mfma_f32_16x16x32_bf16(Ah[1], B1, z, 0, 0, 0);
            const float gi = a0.x + a1.x;
            const float gf = a0.y + a1.y;
            const float gg = a0.z + a1.z;
            const float go = a0.w + a1.w;

            const float Ei = __builtin_amdgcn_exp2f(-gi);
            const float Ef = __builtin_amdgcn_exp2f(-gf);
            const float Eg = __builtin_amdgcn_exp2f(gg);
            const float Eo = __builtin_amdgcn_exp2f(-go);
            const float DIG = (1.f + Ei) * (1.f + Eg);
            const float DF  = 1.f + Ef;
            const float t1  = fmaf(K2C, Eg, -K2C);          // K2*(Eg-1)
            const float num = fmaf(cs, DIG, t1 * DF);
            cs = num * __builtin_amdgcn_rcpf(DF * DIG);     // 2*log2e*c_t
            const float Ec = __builtin_amdgcn_exp2f(cs);
            const float h  = (Ec - 1.f) *
                             __builtin_amdgcn_rcpf((1.f + Eo) * (1.f + Ec));
            if (uo < HID)
                Hh[1 - p][col][uo] = bf16_rtne(h);
        } else {
            // ---- chore wave: x slots, y via MFMA, y store ----
            const unsigned short* hrow = &Hh[p][col][0];
            const bf16x8 B0 = *(const bf16x8*)&hrow[quad * 8];
            const bf16x8 B1 = *(const bf16x8*)&hrow[32 + quad * 8];

            if (lane >= 16 && lane < 16 + BT) {
                // x_{t+1} slots from register xa; prefetch x[b][t+2]
                const int b = lane - 16;
                const unsigned short hx = bf16_rtne(xa);
                const unsigned short lx = bf16_rtne(xa - bf16_f32(hx));
                unsigned* row32 = (unsigned*)&Hh[1 - p][b][0];
                row32[25] = (unsigned)hx | (0x3F80u << 16);   // k=50,51
                row32[26] = (unsigned)lx | (0x3F80u << 16);   // k=52,53
                Hh[1 - p][b][54] = hx;                        // k=54
                xa = xrow[(t + 2 < TT) ? t + 2 : TT - 1];
            }

            const f32x4 z = {0.f, 0.f, 0.f, 0.f};
            f32x4 a0 = __builtin_amdgcn_mfma_f32_16x16x32_bf16(Ah[0], B0, z, 0, 0, 0);
            a0 = __builtin_amdgcn_mfma_f32_16x16x32_bf16(Ah[1], B1, a0, 0, 0, 0);
            // D row0 (hi) + row1 (lo) live in acc.x/acc.y of lanes 0..15
            if (lane < BT && t > 0)
                yout[(size_t)lane * TT + (t - 1)] = a0.x + a0.y + bo;
        }

        __syncthreads();    // the ONE barrier
    }

    // epilogue: y_{TT-1} from Hh[0] (h_{511})
    if (wv == NCW) {
        const unsigned short* hrow = &Hh[0][col][0];
        const bf16x8 B0 = *(const bf16x8*)&hrow[quad * 8];
        const bf16x8 B1 = *(const bf16x8*)&hrow[32 + quad * 8];
        const f32x4 z = {0.f, 0.f, 0.f, 0.f};
        f32x4 a0 = __builtin_amdgcn_mfma_f32_16x16x32_bf16(Ah[0], B0, z, 0, 0, 0);
        a0 = __builtin_amdgcn_mfma_f32_16x16x32_bf16(Ah[1], B1, a0, 0, 0, 0);
        if (lane < BT)
            yout[(size_t)lane * TT + (TT - 1)] = a0.x + a0.y + bo;
    }
}

extern "C" void kernel_launch(void* const* d_in, const int* in_sizes, int n_in,
                              void* d_out, int out_size, void* d_ws, size_t ws_size,
                              hipStream_t stream) {
    const float* x     = (const float*)d_in[0];
    const float* W_ih  = (const float*)d_in[1];
    const float* W_hh  = (const float*)d_in[2];
    const float* b_ih  = (const float*)d_in[3];
    const float* b_hh  = (const float*)d_in[4];
    const float* W_out = (const float*)d_in[5];
    const float* b_out = (const float*)d_in[6];
    float* out = (float*)d_out;

    const int B = in_sizes[0] / TT;          // 4096
    lstm_mfma12_kernel<<<B / BT, NTH, 0, stream>>>(x, W_ih, W_hh, b_ih, b_hh,
                                                   W_out, b_out, out);
}

// Round 8
// 261.636 us; speedup vs baseline: 1.4130x; 1.4130x over previous
//
#include <hip/hip_runtime.h>
#include <math.h>

#define HID 50
#define TT  512
#define BT  16      // batch per block (= MFMA N)
#define NCW 13      // compute waves, one 16-row M-tile each; wave 13 = chore
#define NTH 896     // 14 waves
#define HS  72      // H plane row stride in shorts (144 B, 16B-aligned)
#define L2E 1.44269504088896f
#define K2C 2.88539008177793f   // 2*log2(e)

typedef __attribute__((ext_vector_type(8))) short bf16x8;
typedef __attribute__((ext_vector_type(4))) float f32x4;

__device__ __forceinline__ unsigned short bf16_rtne(float f) {
    unsigned u = __float_as_uint(f);
    u = (u + 0x7FFFu + ((u >> 16) & 1u)) >> 16;
    return (unsigned short)u;
}
__device__ __forceinline__ float bf16_f32(unsigned short s) {
    return __uint_as_float(((unsigned)s) << 16);
}

// R20 = R13 (the proven 221 µs kernel: 13 compute waves x 1 tile, BT=16,
// 1 block/CU, p-indexed double buffer) with EXACTLY ONE change:
// the loop barrier is `s_waitcnt lgkmcnt(0); s_barrier` instead of
// __syncthreads().
//
// Why: __syncthreads() emits s_waitcnt vmcnt(0) ... before s_barrier.
// Compute waves have no outstanding vmem, but the CHORE wave issues a
// global y-store mid-step; vmcnt(0) forces that store to retire to L2
// (~150-300 cy) before the chore arrives at the barrier, and the whole
// block waits for the last arrival -> serialized per-step tax.
// Correctness only needs LDS visibility (h + x-slot writes), which
// lgkmcnt(0) covers; the store/load stay in flight across steps.
// R15 tested this bundled with sched_barrier(0) + pointer ping-pong and
// regressed; m141 says order-pinning is its own regression mechanism, so
// this is the clean single-variable decomposition.
// R16's BT=8/2-blocks-per-CU is REFUTED (336 µs): per-block VALU work
// doesn't scale with BT; phantom lanes doubled per-CU issue.
//
// Math (A rows pre-scaled by log2e for i,f,o / 2*log2e for g):
//   Ei=2^-i', Ef=2^-f', Eg=2^g', Eo=2^-o'
//   cs = [cs*(1+Ei)(1+Eg) + K2*(Eg-1)*(1+Ef)] * rcp((1+Ef)(1+Ei)(1+Eg))
//   Ec = 2^cs;  h = (Ec-1) * rcp((1+Eo)(1+Ec))
// K-slots: 0..49 = s*W_hh | 50 = (s*Wih)_hi (x_hi) | 51 = (s*bias)_hi (1.0)
//          52 = (s*Wih)_hi (x_lo) | 53 = (s*bias)_lo (1.0) | 54 = (s*Wih)_lo (x_hi)
__global__ __launch_bounds__(NTH, 1) void lstm_mfma13_kernel(
    const float* __restrict__ x,      // [B, T]
    const float* __restrict__ W_ih,   // [200, 1]
    const float* __restrict__ W_hh,   // [200, 50]
    const float* __restrict__ b_ih,   // [200]
    const float* __restrict__ b_hh,   // [200]
    const float* __restrict__ W_out,  // [1, 50]
    const float* __restrict__ b_out,  // [1]
    float* __restrict__ out)          // [B, T]
{
    const int tid  = threadIdx.x;
    const int lane = tid & 63;
    const int wv   = tid >> 6;       // 0..13
    const int col  = lane & 15;      // A-m / B-n(batch) / D-col(batch)
    const int quad = lane >> 4;      // k-octet / D row-group

    __shared__ __align__(16) unsigned short Hh[2][BT][HS];

    // zero both H buffers (k-slots 55..63 + pads stay 0)
    for (int i = tid; i < 2 * BT * HS; i += NTH)
        (&Hh[0][0][0])[i] = 0;

    // persistent A fragments (single plane, PRE-SCALED rows)
    bf16x8 Ah[2];
    float cs = 0.f;                            // 2*log2e * c
    const int uo = wv * 4 + quad;              // output unit of this lane

    if (wv < NCW) {
        const int gh  = wv * 16 + col;          // g^ row
        const int u   = gh >> 2;
        const int ty  = gh & 3;
        const bool vl = (u < HID);
        const int og  = ty * HID + u;           // original gate row
        const float sc = (ty == 2) ? K2C : L2E;
        #pragma unroll
        for (int kk = 0; kk < 2; ++kk) {
            #pragma unroll
            for (int j = 0; j < 8; ++j) {
                const int k = kk * 32 + quad * 8 + j;
                float v = 0.f;
                if (vl) {
                    if (k < HID)      v = sc * W_hh[og * HID + k];
                    else if (k == 50) v = sc * W_ih[og];
                    else if (k == 51) v = sc * (b_ih[og] + b_hh[og]);
                    else if (k == 52) v = sc * W_ih[og];
                    else if (k == 53) {
                        const float sb = sc * (b_ih[og] + b_hh[og]);
                        v = sb - bf16_f32(bf16_rtne(sb));
                    } else if (k == 54) {
                        const float sw = sc * W_ih[og];
                        v = sw - bf16_f32(bf16_rtne(sw));
                    }
                }
                Ah[kk][j] = (short)bf16_rtne(v);
            }
        }
    } else {
        // chore wave: A row0 = hi(W_out), row1 = W_out - hi(W_out)
        #pragma unroll
        for (int kk = 0; kk < 2; ++kk) {
            #pragma unroll
            for (int j = 0; j < 8; ++j) {
                const int k = kk * 32 + quad * 8 + j;
                const float v = (k < HID) ? W_out[k] : 0.f;
                const unsigned short hi = bf16_rtne(v);
                short val = 0;
                if (col == 0)      val = (short)hi;
                else if (col == 1) val = (short)bf16_rtne(v - bf16_f32(hi));
                Ah[kk][j] = val;
            }
        }
    }
    const float bo = b_out[0];
    float* yout = out + (size_t)blockIdx.x * BT * TT;

    // chore-wave x pipeline state (lanes 16..31 own batch b = lane-16)
    const int xb = (lane >= 16) ? (lane - 16) : 0;
    const float* xrow = x + (size_t)(blockIdx.x * BT + xb) * TT;
    float xa = 0.f;
    if (wv == NCW && lane >= 16 && lane < 32)
        xa = xrow[1];                            // x[b][1] for step t=0's write

    __syncthreads();    // zeroed H visible

    // buffer-0 slots for t=0: x_0 hi/lo + bias-1.0 markers (packed b32 writes)
    if (tid < BT) {
        const float x0 = x[(size_t)(blockIdx.x * BT + tid) * TT];
        const unsigned short hx = bf16_rtne(x0);
        const unsigned short lx = bf16_rtne(x0 - bf16_f32(hx));
        unsigned* row32 = (unsigned*)&Hh[0][tid][0];
        row32[25] = (unsigned)hx | (0x3F80u << 16);   // k=50,51
        row32[26] = (unsigned)lx | (0x3F80u << 16);   // k=52,53
        Hh[0][tid][54] = hx;                          // k=54
    }
    __syncthreads();

    for (int t = 0; t < TT; ++t) {
        const int p = t & 1;        // read buffer; write 1-p

        if (wv < NCW) {
            // ---- compute wave: one tile ----
            const unsigned short* hrow = &Hh[p][col][0];
            const bf16x8 B0 = *(const bf16x8*)&hrow[quad * 8];
            const bf16x8 B1 = *(const bf16x8*)&hrow[32 + quad * 8];

            const f32x4 z = {0.f, 0.f, 0.f, 0.f};
            f32x4 a0 = __builtin_amdgcn_mfma_f32_16x16x32_bf16(Ah[0], B0, z, 0, 0, 0);
            f32x4 a1 = __builtin_amdgcn_mfma_f32_16x16x32_bf16(Ah[1], B1, z, 0, 0, 0);
            const float gi = a0.x + a1.x;
            const float gf = a0.y + a1.y;
            const float gg = a0.z + a1.z;
            const float go = a0.w + a1.w;

            const float Ei = __builtin_amdgcn_exp2f(-gi);
            const float Ef = __builtin_amdgcn_exp2f(-gf);
            const float Eg = __builtin_amdgcn_exp2f(gg);
            const float Eo = __builtin_amdgcn_exp2f(-go);
            const float DIG = (1.f + Ei) * (1.f + Eg);
            const float DF  = 1.f + Ef;
            const float t1  = fmaf(K2C, Eg, -K2C);          // K2*(Eg-1)
            const float num = fmaf(cs, DIG, t1 * DF);
            cs = num * __builtin_amdgcn_rcpf(DF * DIG);     // 2*log2e*c_t
            const float Ec = __builtin_amdgcn_exp2f(cs);
            const float h  = (Ec - 1.f) *
                             __builtin_amdgcn_rcpf((1.f + Eo) * (1.f + Ec));
            if (uo < HID)
                Hh[1 - p][col][uo] = bf16_rtne(h);
        } else {
            // ---- chore wave: x slots, y via MFMA, y store ----
            const unsigned short* hrow = &Hh[p][col][0];
            const bf16x8 B0 = *(const bf16x8*)&hrow[quad * 8];
            const bf16x8 B1 = *(const bf16x8*)&hrow[32 + quad * 8];

            if (lane >= 16 && lane < 32) {
                // x_{t+1} slots from register xa; prefetch x[b][t+2]
                const int b = lane - 16;
                const unsigned short hx = bf16_rtne(xa);
                const unsigned short lx = bf16_rtne(xa - bf16_f32(hx));
                unsigned* row32 = (unsigned*)&Hh[1 - p][b][0];
                row32[25] = (unsigned)hx | (0x3F80u << 16);   // k=50,51
                row32[26] = (unsigned)lx | (0x3F80u << 16);   // k=52,53
                Hh[1 - p][b][54] = hx;                        // k=54
                xa = xrow[(t + 2 < TT) ? t + 2 : TT - 1];
            }

            const f32x4 z = {0.f, 0.f, 0.f, 0.f};
            f32x4 a0 = __builtin_amdgcn_mfma_f32_16x16x32_bf16(Ah[0], B0, z, 0, 0, 0);
            a0 = __builtin_amdgcn_mfma_f32_16x16x32_bf16(Ah[1], B1, a0, 0, 0, 0);
            // D row0 (hi) + row1 (lo) live in acc.x/acc.y of lanes 0..15
            if (lane < 16 && t > 0)
                yout[(size_t)lane * TT + (t - 1)] = a0.x + a0.y + bo;
        }

        // the ONE barrier — LDS-drain only. Correctness needs h + x-slot
        // LDS writes visible; the chore's global y-store / x-load stay in
        // flight (vmcnt NOT drained; compute waves have no vmem anyway).
        asm volatile("s_waitcnt lgkmcnt(0)\n\ts_barrier" ::: "memory");
    }

    // epilogue: y_{TT-1} from Hh[0] (h_{511})
    if (wv == NCW) {
        const unsigned short* hrow = &Hh[0][col][0];
        const bf16x8 B0 = *(const bf16x8*)&hrow[quad * 8];
        const bf16x8 B1 = *(const bf16x8*)&hrow[32 + quad * 8];
        const f32x4 z = {0.f, 0.f, 0.f, 0.f};
        f32x4 a0 = __builtin_amdgcn_mfma_f32_16x16x32_bf16(Ah[0], B0, z, 0, 0, 0);
        a0 = __builtin_amdgcn_mfma_f32_16x16x32_bf16(Ah[1], B1, a0, 0, 0, 0);
        if (lane < 16)
            yout[(size_t)lane * TT + (TT - 1)] = a0.x + a0.y + bo;
    }
}

extern "C" void kernel_launch(void* const* d_in, const int* in_sizes, int n_in,
                              void* d_out, int out_size, void* d_ws, size_t ws_size,
                              hipStream_t stream) {
    const float* x     = (const float*)d_in[0];
    const float* W_ih  = (const float*)d_in[1];
    const float* W_hh  = (const float*)d_in[2];
    const float* b_ih  = (const float*)d_in[3];
    const float* b_hh  = (const float*)d_in[4];
    const float* W_out = (const float*)d_in[5];
    const float* b_out = (const float*)d_in[6];
    float* out = (float*)d_out;

    const int B = in_sizes[0] / TT;          // 4096
    lstm_mfma13_kernel<<<B / BT, NTH, 0, stream>>>(x, W_ih, W_hh, b_ih, b_hh,
                                                   W_out, b_out, out);
}

// Round 9
// 249.108 us; speedup vs baseline: 1.4841x; 1.0503x over previous
//
#include <hip/hip_runtime.h>
#include <math.h>

#define HID 50
#define TT  512
#define BT  16      // batch per block (= MFMA N)
#define NCW 13      // compute waves, one 16-row M-tile each; wave 13 = chore
#define NTH 896     // 14 waves
#define HS  72      // H plane row stride in shorts (144 B, 16B-aligned)
#define L2E 1.44269504088896f
#define K2C 2.88539008177793f   // 2*log2(e)

typedef __attribute__((ext_vector_type(8))) short bf16x8;
typedef __attribute__((ext_vector_type(4))) float f32x4;

__device__ __forceinline__ unsigned short bf16_rtne(float f) {
    unsigned u = __float_as_uint(f);
    u = (u + 0x7FFFu + ((u >> 16) & 1u)) >> 16;
    return (unsigned short)u;
}
__device__ __forceinline__ float bf16_f32(unsigned short s) {
    return __uint_as_float(((unsigned)s) << 16);
}

// R21 = R20 (215 µs: R13 structure + lgkm-only barrier) + per-step
// instruction-count trim. R20's counters: VALUBusy 51.5% = ~74 inst/wave/step
// vs ~30 of real math -> overhead is addressing/branch/rounding:
//  - unroll x2: even/odd steps use hoisted per-lane plane pointers
//    (rdA/rdB/wrA/wrB), no p-indexed address math per iter.
//  - unconditional h-write: uo 50,51 (phantom, A rows zero -> h==0)
//    redirected to unused zero slots 55,56, hoisted -> no divergent branch.
//  - h bf16 rounding via ONE v_cvt_pk_bf16_f32 (RTNE) instead of 3-op
//    manual round (chore x-path keeps manual for setup consistency).
//  - zero-acc + y/x pointers hoisted.
// Barrier stays `s_waitcnt lgkmcnt(0); s_barrier` (R20 proved +3%).
// R16's 2-blocks/CU REFUTED (336 µs): per-block VALU doesn't scale w/ BT.
//
// Math (A rows pre-scaled by log2e for i,f,o / 2*log2e for g):
//   Ei=2^-i', Ef=2^-f', Eg=2^g', Eo=2^-o'
//   cs = [cs*(1+Ei)(1+Eg) + K2*(Eg-1)*(1+Ef)] * rcp((1+Ef)(1+Ei)(1+Eg))
//   Ec = 2^cs;  h = (Ec-1) * rcp((1+Eo)(1+Ec))
// K-slots: 0..49 = s*W_hh | 50 = (s*Wih)_hi (x_hi) | 51 = (s*bias)_hi (1.0)
//          52 = (s*Wih)_hi (x_lo) | 53 = (s*bias)_lo (1.0) | 54 = (s*Wih)_lo (x_hi)
//          55,56 = phantom-h dump (always 0; A zero there)
__global__ __launch_bounds__(NTH, 1) void lstm_mfma14_kernel(
    const float* __restrict__ x,      // [B, T]
    const float* __restrict__ W_ih,   // [200, 1]
    const float* __restrict__ W_hh,   // [200, 50]
    const float* __restrict__ b_ih,   // [200]
    const float* __restrict__ b_hh,   // [200]
    const float* __restrict__ W_out,  // [1, 50]
    const float* __restrict__ b_out,  // [1]
    float* __restrict__ out)          // [B, T]
{
    const int tid  = threadIdx.x;
    const int lane = tid & 63;
    const int wv   = tid >> 6;       // 0..13
    const int col  = lane & 15;      // A-m / B-n(batch) / D-col(batch)
    const int quad = lane >> 4;      // k-octet / D row-group

    __shared__ __align__(16) unsigned short Hh[2][BT][HS];

    // zero both H buffers (k-slots 55..63 + pads stay 0)
    for (int i = tid; i < 2 * BT * HS; i += NTH)
        (&Hh[0][0][0])[i] = 0;

    // persistent A fragments (single plane, PRE-SCALED rows)
    bf16x8 Ah[2];
    float cs = 0.f;                            // 2*log2e * c
    const int uo  = wv * 4 + quad;             // output unit of this lane
    const int uo2 = (uo < HID) ? uo : uo + 5;  // 50,51 -> 55,56 (harmless)

    if (wv < NCW) {
        const int gh  = wv * 16 + col;          // g^ row
        const int u   = gh >> 2;
        const int ty  = gh & 3;
        const bool vl = (u < HID);
        const int og  = ty * HID + u;           // original gate row
        const float sc = (ty == 2) ? K2C : L2E;
        #pragma unroll
        for (int kk = 0; kk < 2; ++kk) {
            #pragma unroll
            for (int j = 0; j < 8; ++j) {
                const int k = kk * 32 + quad * 8 + j;
                float v = 0.f;
                if (vl) {
                    if (k < HID)      v = sc * W_hh[og * HID + k];
                    else if (k == 50) v = sc * W_ih[og];
                    else if (k == 51) v = sc * (b_ih[og] + b_hh[og]);
                    else if (k == 52) v = sc * W_ih[og];
                    else if (k == 53) {
                        const float sb = sc * (b_ih[og] + b_hh[og]);
                        v = sb - bf16_f32(bf16_rtne(sb));
                    } else if (k == 54) {
                        const float sw = sc * W_ih[og];
                        v = sw - bf16_f32(bf16_rtne(sw));
                    }
                }
                Ah[kk][j] = (short)bf16_rtne(v);
            }
        }
    } else {
        // chore wave: A row0 = hi(W_out), row1 = W_out - hi(W_out)
        #pragma unroll
        for (int kk = 0; kk < 2; ++kk) {
            #pragma unroll
            for (int j = 0; j < 8; ++j) {
                const int k = kk * 32 + quad * 8 + j;
                const float v = (k < HID) ? W_out[k] : 0.f;
                const unsigned short hi = bf16_rtne(v);
                short val = 0;
                if (col == 0)      val = (short)hi;
                else if (col == 1) val = (short)bf16_rtne(v - bf16_f32(hi));
                Ah[kk][j] = val;
            }
        }
    }
    const float bo = b_out[0];
    float* yout = out + (size_t)blockIdx.x * BT * TT + (size_t)(lane & 15) * TT;

    // chore-wave x pipeline state (lanes 16..31 own batch b = lane-16)
    const int xb = (lane >= 16) ? (lane - 16) : 0;
    const float* xrow = x + (size_t)(blockIdx.x * BT + xb) * TT;
    float xa = 0.f;
    if (wv == NCW && lane >= 16 && lane < 32)
        xa = xrow[1];                            // x[b][1] for step t=0's write

    __syncthreads();    // zeroed H visible

    // buffer-0 slots for t=0: x_0 hi/lo + bias-1.0 markers (packed b32 writes)
    if (tid < BT) {
        const float x0 = x[(size_t)(blockIdx.x * BT + tid) * TT];
        const unsigned short hx = bf16_rtne(x0);
        const unsigned short lx = bf16_rtne(x0 - bf16_f32(hx));
        unsigned* row32 = (unsigned*)&Hh[0][tid][0];
        row32[25] = (unsigned)hx | (0x3F80u << 16);   // k=50,51
        row32[26] = (unsigned)lx | (0x3F80u << 16);   // k=52,53
        Hh[0][tid][54] = hx;                          // k=54
    }
    __syncthreads();

    // hoisted per-lane pointers (loop-invariant)
    const unsigned short* rdA = &Hh[0][col][quad * 8];   // read plane 0
    const unsigned short* rdB = &Hh[1][col][quad * 8];   // read plane 1
    unsigned short* wrA = &Hh[1][col][uo2];              // write when reading 0
    unsigned short* wrB = &Hh[0][col][uo2];              // write when reading 1
    unsigned* xwA = (unsigned*)&Hh[1][xb][0];
    unsigned* xwB = (unsigned*)&Hh[0][xb][0];
    const f32x4 z = {0.f, 0.f, 0.f, 0.f};

#define LSTM_STEP(RD, WR, XW, TI)                                             \
    do {                                                                      \
        if (wv < NCW) {                                                       \
            const bf16x8 B0 = *(const bf16x8*)(RD);                           \
            const bf16x8 B1 = *(const bf16x8*)((RD) + 32);                    \
            f32x4 a0 = __builtin_amdgcn_mfma_f32_16x16x32_bf16(Ah[0], B0, z, 0, 0, 0); \
            f32x4 a1 = __builtin_amdgcn_mfma_f32_16x16x32_bf16(Ah[1], B1, z, 0, 0, 0); \
            const float gi = a0.x + a1.x;                                     \
            const float gf = a0.y + a1.y;                                     \
            const float gg = a0.z + a1.z;                                     \
            const float go = a0.w + a1.w;                                     \
            const float Ei = __builtin_amdgcn_exp2f(-gi);                     \
            const float Ef = __builtin_amdgcn_exp2f(-gf);                     \
            const float Eg = __builtin_amdgcn_exp2f(gg);                      \
            const float Eo = __builtin_amdgcn_exp2f(-go);                     \
            const float DIG = (1.f + Ei) * (1.f + Eg);                        \
            const float DF  = 1.f + Ef;                                       \
            const float t1  = fmaf(K2C, Eg, -K2C);                            \
            const float num = fmaf(cs, DIG, t1 * DF);                         \
            cs = num * __builtin_amdgcn_rcpf(DF * DIG);                       \
            const float Ec = __builtin_amdgcn_exp2f(cs);                      \
            const float h  = (Ec - 1.f) *                                     \
                             __builtin_amdgcn_rcpf((1.f + Eo) * (1.f + Ec));  \
            unsigned hpk;                                                     \
            asm("v_cvt_pk_bf16_f32 %0, %1, %2" : "=v"(hpk) : "v"(h), "v"(h)); \
            *(WR) = (unsigned short)hpk;                                      \
        } else {                                                              \
            const bf16x8 B0 = *(const bf16x8*)(RD);                           \
            const bf16x8 B1 = *(const bf16x8*)((RD) + 32);                    \
            if (lane >= 16 && lane < 32) {                                    \
                const unsigned short hx = bf16_rtne(xa);                      \
                const unsigned short lx = bf16_rtne(xa - bf16_f32(hx));       \
                (XW)[25] = (unsigned)hx | (0x3F80u << 16);                    \
                (XW)[26] = (unsigned)lx | (0x3F80u << 16);                    \
                ((unsigned short*)(XW))[54] = hx;                             \
                xa = xrow[((TI) + 2 < TT) ? (TI) + 2 : TT - 1];               \
            }                                                                 \
            f32x4 a0 = __builtin_amdgcn_mfma_f32_16x16x32_bf16(Ah[0], B0, z, 0, 0, 0); \
            a0 = __builtin_amdgcn_mfma_f32_16x16x32_bf16(Ah[1], B1, a0, 0, 0, 0); \
            if (lane < 16 && (TI) > 0)                                        \
                yout[(TI) - 1] = a0.x + a0.y + bo;                            \
        }                                                                     \
    } while (0)

    for (int t = 0; t < TT; t += 2) {
        LSTM_STEP(rdA, wrA, xwA, t);        // read plane 0, write plane 1
        asm volatile("s_waitcnt lgkmcnt(0)\n\ts_barrier" ::: "memory");
        LSTM_STEP(rdB, wrB, xwB, t + 1);    // read plane 1, write plane 0
        asm volatile("s_waitcnt lgkmcnt(0)\n\ts_barrier" ::: "memory");
    }
#undef LSTM_STEP

    // epilogue: y_{TT-1} from plane 0 (h_{511})
    if (wv == NCW) {
        const bf16x8 B0 = *(const bf16x8*)rdA;
        const bf16x8 B1 = *(const bf16x8*)(rdA + 32);
        f32x4 a0 = __builtin_amdgcn_mfma_f32_16x16x32_bf16(Ah[0], B0, z, 0, 0, 0);
        a0 = __builtin_amdgcn_mfma_f32_16x16x32_bf16(Ah[1], B1, a0, 0, 0, 0);
        if (lane < 16)
            yout[TT - 1] = a0.x + a0.y + bo;
    }
}

extern "C" void kernel_launch(void* const* d_in, const int* in_sizes, int n_in,
                              void* d_out, int out_size, void* d_ws, size_t ws_size,
                              hipStream_t stream) {
    const float* x     = (const float*)d_in[0];
    const float* W_ih  = (const float*)d_in[1];
    const float* W_hh  = (const float*)d_in[2];
    const float* b_ih  = (const float*)d_in[3];
    const float* b_hh  = (const float*)d_in[4];
    const float* W_out = (const float*)d_in[5];
    const float* b_out = (const float*)d_in[6];
    float* out = (float*)d_out;

    const int B = in_sizes[0] / TT;          // 4096
    lstm_mfma14_kernel<<<B / BT, NTH, 0, stream>>>(x, W_ih, W_hh, b_ih, b_hh,
                                                   W_out, b_out, out);
}

// Round 11
// 241.068 us; speedup vs baseline: 1.5336x; 1.0333x over previous
//
#include <hip/hip_runtime.h>
#include <math.h>

#define HID 50
#define TT  512
#define BT  16      // batch per block (= MFMA N)
#define NCW 13      // compute waves, one 16-row M-tile each; wave 13 = chore
#define NTH 896     // 14 waves
#define HS  72      // H plane row stride in shorts (144 B, 16B-aligned)
#define L2E 1.44269504088896f
#define K2C 2.88539008177793f   // 2*log2(e)

typedef __attribute__((ext_vector_type(8))) short bf16x8;
typedef __attribute__((ext_vector_type(4))) float f32x4;

__device__ __forceinline__ unsigned short bf16_rtne(float f) {
    unsigned u = __float_as_uint(f);
    u = (u + 0x7FFFu + ((u >> 16) & 1u)) >> 16;
    return (unsigned short)u;
}
__device__ __forceinline__ float bf16_f32(unsigned short s) {
    return __uint_as_float(((unsigned)s) << 16);
}

// R23 = R21 (200 µs, PASSED: R13 structure + lgkm-only barrier + unroll x2 +
// hoisted pointers + cvt_pk h-round) + ONE safe change: compute-wave MFMAs
// are C-CHAINED (acc = mfma(Ah[1],B1, mfma(Ah[0],B0,z))), deleting the 4
// cross-accumulator VALU adds per wave-step (issue-bound regime; math
// identity up to f32 accumulate rounding).
// R22's wave-12 y-fold (13 waves, W_out in phantom A rows) FAILED with
// absmax=NaN — could not isolate the poison path by inspection; shelved.
// s_setprio deliberately NOT used: m190 measured null-to-negative in
// barrier-lockstep structures.
//
// Math (A rows pre-scaled by log2e for i,f,o / 2*log2e for g):
//   Ei=2^-i', Ef=2^-f', Eg=2^g', Eo=2^-o'
//   cs = [cs*(1+Ei)(1+Eg) + K2*(Eg-1)*(1+Ef)] * rcp((1+Ef)(1+Ei)(1+Eg))
//   Ec = 2^cs;  h = (Ec-1) * rcp((1+Eo)(1+Ec))
// K-slots: 0..49 = s*W_hh | 50 = (s*Wih)_hi (x_hi) | 51 = (s*bias)_hi (1.0)
//          52 = (s*Wih)_hi (x_lo) | 53 = (s*bias)_lo (1.0) | 54 = (s*Wih)_lo (x_hi)
//          55,56 = phantom-h dump (always 0; A zero there)
__global__ __launch_bounds__(NTH, 1) void lstm_mfma16_kernel(
    const float* __restrict__ x,      // [B, T]
    const float* __restrict__ W_ih,   // [200, 1]
    const float* __restrict__ W_hh,   // [200, 50]
    const float* __restrict__ b_ih,   // [200]
    const float* __restrict__ b_hh,   // [200]
    const float* __restrict__ W_out,  // [1, 50]
    const float* __restrict__ b_out,  // [1]
    float* __restrict__ out)          // [B, T]
{
    const int tid  = threadIdx.x;
    const int lane = tid & 63;
    const int wv   = tid >> 6;       // 0..13
    const int col  = lane & 15;      // A-m / B-n(batch) / D-col(batch)
    const int quad = lane >> 4;      // k-octet / D row-group

    __shared__ __align__(16) unsigned short Hh[2][BT][HS];

    // zero both H buffers (k-slots 55..63 + pads stay 0)
    for (int i = tid; i < 2 * BT * HS; i += NTH)
        (&Hh[0][0][0])[i] = 0;

    // persistent A fragments (single plane, PRE-SCALED rows)
    bf16x8 Ah[2];
    float cs = 0.f;                            // 2*log2e * c
    const int uo  = wv * 4 + quad;             // output unit of this lane
    const int uo2 = (uo < HID) ? uo : uo + 5;  // 50,51 -> 55,56 (harmless)

    if (wv < NCW) {
        const int gh  = wv * 16 + col;          // g^ row
        const int u   = gh >> 2;
        const int ty  = gh & 3;
        const bool vl = (u < HID);
        const int og  = ty * HID + u;           // original gate row
        const float sc = (ty == 2) ? K2C : L2E;
        #pragma unroll
        for (int kk = 0; kk < 2; ++kk) {
            #pragma unroll
            for (int j = 0; j < 8; ++j) {
                const int k = kk * 32 + quad * 8 + j;
                float v = 0.f;
                if (vl) {
                    if (k < HID)      v = sc * W_hh[og * HID + k];
                    else if (k == 50) v = sc * W_ih[og];
                    else if (k == 51) v = sc * (b_ih[og] + b_hh[og]);
                    else if (k == 52) v = sc * W_ih[og];
                    else if (k == 53) {
                        const float sb = sc * (b_ih[og] + b_hh[og]);
                        v = sb - bf16_f32(bf16_rtne(sb));
                    } else if (k == 54) {
                        const float sw = sc * W_ih[og];
                        v = sw - bf16_f32(bf16_rtne(sw));
                    }
                }
                Ah[kk][j] = (short)bf16_rtne(v);
            }
        }
    } else {
        // chore wave: A row0 = hi(W_out), row1 = W_out - hi(W_out)
        #pragma unroll
        for (int kk = 0; kk < 2; ++kk) {
            #pragma unroll
            for (int j = 0; j < 8; ++j) {
                const int k = kk * 32 + quad * 8 + j;
                const float v = (k < HID) ? W_out[k] : 0.f;
                const unsigned short hi = bf16_rtne(v);
                short val = 0;
                if (col == 0)      val = (short)hi;
                else if (col == 1) val = (short)bf16_rtne(v - bf16_f32(hi));
                Ah[kk][j] = val;
            }
        }
    }
    const float bo = b_out[0];
    float* yout = out + (size_t)blockIdx.x * BT * TT + (size_t)(lane & 15) * TT;

    // chore-wave x pipeline state (lanes 16..31 own batch b = lane-16)
    const int xb = (lane >= 16) ? (lane - 16) : 0;
    const float* xrow = x + (size_t)(blockIdx.x * BT + xb) * TT;
    float xa = 0.f;
    if (wv == NCW && lane >= 16 && lane < 32)
        xa = xrow[1];                            // x[b][1] for step t=0's write

    __syncthreads();    // zeroed H visible

    // buffer-0 slots for t=0: x_0 hi/lo + bias-1.0 markers (packed b32 writes)
    if (tid < BT) {
        const float x0 = x[(size_t)(blockIdx.x * BT + tid) * TT];
        const unsigned short hx = bf16_rtne(x0);
        const unsigned short lx = bf16_rtne(x0 - bf16_f32(hx));
        unsigned* row32 = (unsigned*)&Hh[0][tid][0];
        row32[25] = (unsigned)hx | (0x3F80u << 16);   // k=50,51
        row32[26] = (unsigned)lx | (0x3F80u << 16);   // k=52,53
        Hh[0][tid][54] = hx;                          // k=54
    }
    __syncthreads();

    // hoisted per-lane pointers (loop-invariant)
    const unsigned short* rdA = &Hh[0][col][quad * 8];   // read plane 0
    const unsigned short* rdB = &Hh[1][col][quad * 8];   // read plane 1
    unsigned short* wrA = &Hh[1][col][uo2];              // write when reading 0
    unsigned short* wrB = &Hh[0][col][uo2];              // write when reading 1
    unsigned* xwA = (unsigned*)&Hh[1][xb][0];
    unsigned* xwB = (unsigned*)&Hh[0][xb][0];
    const f32x4 z = {0.f, 0.f, 0.f, 0.f};

#define LSTM_STEP(RD, WR, XW, TI)                                             \
    do {                                                                      \
        if (wv < NCW) {                                                       \
            const bf16x8 B0 = *(const bf16x8*)(RD);                           \
            const bf16x8 B1 = *(const bf16x8*)((RD) + 32);                    \
            f32x4 a0 = __builtin_amdgcn_mfma_f32_16x16x32_bf16(Ah[0], B0, z, 0, 0, 0); \
            a0 = __builtin_amdgcn_mfma_f32_16x16x32_bf16(Ah[1], B1, a0, 0, 0, 0); \
            const float Ei = __builtin_amdgcn_exp2f(-a0.x);                   \
            const float Ef = __builtin_amdgcn_exp2f(-a0.y);                   \
            const float Eg = __builtin_amdgcn_exp2f(a0.z);                    \
            const float Eo = __builtin_amdgcn_exp2f(-a0.w);                   \
            const float DIG = (1.f + Ei) * (1.f + Eg);                        \
            const float DF  = 1.f + Ef;                                       \
            const float t1  = fmaf(K2C, Eg, -K2C);                            \
            const float num = fmaf(cs, DIG, t1 * DF);                         \
            cs = num * __builtin_amdgcn_rcpf(DF * DIG);                       \
            const float Ec = __builtin_amdgcn_exp2f(cs);                      \
            const float h  = (Ec - 1.f) *                                     \
                             __builtin_amdgcn_rcpf((1.f + Eo) * (1.f + Ec));  \
            unsigned hpk;                                                     \
            asm("v_cvt_pk_bf16_f32 %0, %1, %2" : "=v"(hpk) : "v"(h), "v"(h)); \
            *(WR) = (unsigned short)hpk;                                      \
        } else {                                                              \
            const bf16x8 B0 = *(const bf16x8*)(RD);                           \
            const bf16x8 B1 = *(const bf16x8*)((RD) + 32);                    \
            if (lane >= 16 && lane < 32) {                                    \
                const unsigned short hx = bf16_rtne(xa);                      \
                const unsigned short lx = bf16_rtne(xa - bf16_f32(hx));       \
                (XW)[25] = (unsigned)hx | (0x3F80u << 16);                    \
                (XW)[26] = (unsigned)lx | (0x3F80u << 16);                    \
                ((unsigned short*)(XW))[54] = hx;                             \
                xa = xrow[((TI) + 2 < TT) ? (TI) + 2 : TT - 1];               \
            }                                                                 \
            f32x4 a0 = __builtin_amdgcn_mfma_f32_16x16x32_bf16(Ah[0], B0, z, 0, 0, 0); \
            a0 = __builtin_amdgcn_mfma_f32_16x16x32_bf16(Ah[1], B1, a0, 0, 0, 0); \
            if (lane < 16 && (TI) > 0)                                        \
                yout[(TI) - 1] = a0.x + a0.y + bo;                            \
        }                                                                     \
    } while (0)

    for (int t = 0; t < TT; t += 2) {
        LSTM_STEP(rdA, wrA, xwA, t);        // read plane 0, write plane 1
        asm volatile("s_waitcnt lgkmcnt(0)\n\ts_barrier" ::: "memory");
        LSTM_STEP(rdB, wrB, xwB, t + 1);    // read plane 1, write plane 0
        asm volatile("s_waitcnt lgkmcnt(0)\n\ts_barrier" ::: "memory");
    }
#undef LSTM_STEP

    // epilogue: y_{TT-1} from plane 0 (h_{511})
    if (wv == NCW) {
        const bf16x8 B0 = *(const bf16x8*)rdA;
        const bf16x8 B1 = *(const bf16x8*)(rdA + 32);
        f32x4 a0 = __builtin_amdgcn_mfma_f32_16x16x32_bf16(Ah[0], B0, z, 0, 0, 0);
        a0 = __builtin_amdgcn_mfma_f32_16x16x32_bf16(Ah[1], B1, a0, 0, 0, 0);
        if (lane < 16)
            yout[TT - 1] = a0.x + a0.y + bo;
    }
}

extern "C" void kernel_launch(void* const* d_in, const int* in_sizes, int n_in,
                              void* d_out, int out_size, void* d_ws, size_t ws_size,
                              hipStream_t stream) {
    const float* x     = (const float*)d_in[0];
    const float* W_ih  = (const float*)d_in[1];
    const float* W_hh  = (const float*)d_in[2];
    const float* b_ih  = (const float*)d_in[3];
    const float* b_hh  = (const float*)d_in[4];
    const float* W_out = (const float*)d_in[5];
    const float* b_out = (const float*)d_in[6];
    float* out = (float*)d_out;

    const int B = in_sizes[0] / TT;          // 4096
    lstm_mfma16_kernel<<<B / BT, NTH, 0, stream>>>(x, W_ih, W_hh, b_ih, b_hh,
                                                   W_out, b_out, out);
}

// Round 12
// 231.961 us; speedup vs baseline: 1.5938x; 1.0393x over previous
//
#include <hip/hip_runtime.h>
#include <math.h>

#define HID 50
#define TT  512
#define BT  16      // batch per block (= MFMA N)
#define NCW 7       // compute waves, TWO 16-row M-tiles each; wave 7 = chore
#define NTH 512     // 8 waves
#define HS  72      // H plane row stride in shorts (144 B, 16B-aligned)
#define L2E 1.44269504088896f
#define K2C 2.88539008177793f   // 2*log2(e)

typedef __attribute__((ext_vector_type(8))) short bf16x8;
typedef __attribute__((ext_vector_type(4))) float f32x4;

__device__ __forceinline__ unsigned short bf16_rtne(float f) {
    unsigned u = __float_as_uint(f);
    u = (u + 0x7FFFu + ((u >> 16) & 1u)) >> 16;
    return (unsigned short)u;
}
__device__ __forceinline__ float bf16_f32(unsigned short s) {
    return __uint_as_float(((unsigned)s) << 16);
}

// R24: halve the LDS-port burst. R23's counters imply the step is bounded
// by 14 waves x 2KB = 28KB of redundant B-fragment reads (~220 cy port
// time) issued in lock-step after each barrier. Go to 7 compute waves x
// TWO tiles (share one B read across both tiles' MFMAs) + 1 chore wave:
// 16KB/step (~125 cy). Per-wave work doubles but the two tile-chains are
// independent (ILP-2 replaces lost TLP); total VALU issue unchanged.
// Carries ALL proven wins: lgkm-only barrier (R20), unroll x2 + hoisted
// pointers + cvt_pk h-round (R21), chained MFMA (R23), chore y-MFMA (R13).
// Tile 13 (rows 208..223) is all-phantom via u<50 zero-fill: gates=0 ->
// h=0 -> dumped to unused slots 57..60. Tile 12's uo=50,51 -> 55,56.
//
// Math (A rows pre-scaled by log2e for i,f,o / 2*log2e for g):
//   Ei=2^-i', Ef=2^-f', Eg=2^g', Eo=2^-o'
//   cs = [cs*(1+Ei)(1+Eg) + K2*(Eg-1)*(1+Ef)] * rcp((1+Ef)(1+Ei)(1+Eg))
//   Ec = 2^cs;  h = (Ec-1) * rcp((1+Eo)(1+Ec))
// K-slots: 0..49 = s*W_hh | 50 = (s*Wih)_hi (x_hi) | 51 = (s*bias)_hi (1.0)
//          52 = (s*Wih)_hi (x_lo) | 53 = (s*bias)_lo (1.0) | 54 = (s*Wih)_lo (x_hi)
//          55..60 = phantom-h dump (always 0; A zero there)
__global__ __launch_bounds__(NTH, 1) void lstm_mfma17_kernel(
    const float* __restrict__ x,      // [B, T]
    const float* __restrict__ W_ih,   // [200, 1]
    const float* __restrict__ W_hh,   // [200, 50]
    const float* __restrict__ b_ih,   // [200]
    const float* __restrict__ b_hh,   // [200]
    const float* __restrict__ W_out,  // [1, 50]
    const float* __restrict__ b_out,  // [1]
    float* __restrict__ out)          // [B, T]
{
    const int tid  = threadIdx.x;
    const int lane = tid & 63;
    const int wv   = tid >> 6;       // 0..7
    const int col  = lane & 15;      // A-m / B-n(batch) / D-col(batch)
    const int quad = lane >> 4;      // k-octet / D row-group

    __shared__ __align__(16) unsigned short Hh[2][BT][HS];

    // zero both H buffers (k-slots 55..63 + pads stay 0)
    for (int i = tid; i < 2 * BT * HS; i += NTH)
        (&Hh[0][0][0])[i] = 0;

    // persistent A fragments: [tile][kk] (single plane, PRE-SCALED rows)
    bf16x8 Ah[2][2];
    float cs0 = 0.f, cs1 = 0.f;                // 2*log2e * c per tile
    // output unit per tile; phantom -> dump slots (55,56 for uo=50,51;
    // 57..60 for tile-13's uo=52..55)
    const int uoa = (wv * 2) * 4 + quad;
    const int uob = (wv * 2 + 1) * 4 + quad;
    const int uo2a = (uoa < HID) ? uoa : uoa + 5;
    const int uo2b = (uob < HID) ? uob : uob + 5;

    if (wv < NCW) {
        #pragma unroll
        for (int i = 0; i < 2; ++i) {
            const int gh  = (wv * 2 + i) * 16 + col;   // g^ row
            const int u   = gh >> 2;
            const int ty  = gh & 3;
            const bool vl = (u < HID);
            const int og  = ty * HID + u;              // original gate row
            const float sc = (ty == 2) ? K2C : L2E;
            #pragma unroll
            for (int kk = 0; kk < 2; ++kk) {
                #pragma unroll
                for (int j = 0; j < 8; ++j) {
                    const int k = kk * 32 + quad * 8 + j;
                    float v = 0.f;
                    if (vl) {
                        if (k < HID)      v = sc * W_hh[og * HID + k];
                        else if (k == 50) v = sc * W_ih[og];
                        else if (k == 51) v = sc * (b_ih[og] + b_hh[og]);
                        else if (k == 52) v = sc * W_ih[og];
                        else if (k == 53) {
                            const float sb = sc * (b_ih[og] + b_hh[og]);
                            v = sb - bf16_f32(bf16_rtne(sb));
                        } else if (k == 54) {
                            const float sw = sc * W_ih[og];
                            v = sw - bf16_f32(bf16_rtne(sw));
                        }
                    }
                    Ah[i][kk][j] = (short)bf16_rtne(v);
                }
            }
        }
    } else {
        // chore wave: A row0 = hi(W_out), row1 = W_out - hi(W_out)
        #pragma unroll
        for (int kk = 0; kk < 2; ++kk) {
            #pragma unroll
            for (int j = 0; j < 8; ++j) {
                const int k = kk * 32 + quad * 8 + j;
                const float v = (k < HID) ? W_out[k] : 0.f;
                const unsigned short hi = bf16_rtne(v);
                short val = 0;
                if (col == 0)      val = (short)hi;
                else if (col == 1) val = (short)bf16_rtne(v - bf16_f32(hi));
                Ah[0][kk][j] = val;
                Ah[1][kk][j] = 0;
            }
        }
    }
    const float bo = b_out[0];
    float* yout = out + (size_t)blockIdx.x * BT * TT + (size_t)(lane & 15) * TT;

    // chore-wave x pipeline state (lanes 16..31 own batch b = lane-16)
    const int xb = (lane >= 16) ? (lane - 16) : 0;
    const float* xrow = x + (size_t)(blockIdx.x * BT + xb) * TT;
    float xa = 0.f;
    if (wv == NCW && lane >= 16 && lane < 32)
        xa = xrow[1];                            // x[b][1] for step t=0's write

    __syncthreads();    // zeroed H visible

    // buffer-0 slots for t=0: x_0 hi/lo + bias-1.0 markers (packed b32 writes)
    if (tid < BT) {
        const float x0 = x[(size_t)(blockIdx.x * BT + tid) * TT];
        const unsigned short hx = bf16_rtne(x0);
        const unsigned short lx = bf16_rtne(x0 - bf16_f32(hx));
        unsigned* row32 = (unsigned*)&Hh[0][tid][0];
        row32[25] = (unsigned)hx | (0x3F80u << 16);   // k=50,51
        row32[26] = (unsigned)lx | (0x3F80u << 16);   // k=52,53
        Hh[0][tid][54] = hx;                          // k=54
    }
    __syncthreads();

    // hoisted per-lane pointers (loop-invariant)
    const unsigned short* rdA = &Hh[0][col][quad * 8];   // read plane 0
    const unsigned short* rdB = &Hh[1][col][quad * 8];   // read plane 1
    unsigned short* wrA0 = &Hh[1][col][uo2a];            // write when reading 0
    unsigned short* wrA1 = &Hh[1][col][uo2b];
    unsigned short* wrB0 = &Hh[0][col][uo2a];            // write when reading 1
    unsigned short* wrB1 = &Hh[0][col][uo2b];
    unsigned* xwA = (unsigned*)&Hh[1][xb][0];
    unsigned* xwB = (unsigned*)&Hh[0][xb][0];
    const f32x4 z = {0.f, 0.f, 0.f, 0.f};

#define GATES(ACC, CS, HOUT)                                                  \
    do {                                                                      \
        const float Ei = __builtin_amdgcn_exp2f(-(ACC).x);                    \
        const float Ef = __builtin_amdgcn_exp2f(-(ACC).y);                    \
        const float Eg = __builtin_amdgcn_exp2f((ACC).z);                     \
        const float Eo = __builtin_amdgcn_exp2f(-(ACC).w);                    \
        const float DIG = (1.f + Ei) * (1.f + Eg);                            \
        const float DF  = 1.f + Ef;                                           \
        const float t1  = fmaf(K2C, Eg, -K2C);                                \
        const float num = fmaf((CS), DIG, t1 * DF);                           \
        (CS) = num * __builtin_amdgcn_rcpf(DF * DIG);                         \
        const float Ec = __builtin_amdgcn_exp2f(CS);                          \
        (HOUT) = (Ec - 1.f) *                                                 \
                 __builtin_amdgcn_rcpf((1.f + Eo) * (1.f + Ec));              \
    } while (0)

#define LSTM_STEP(RD, WR0, WR1, XW, TI)                                       \
    do {                                                                      \
        if (wv < NCW) {                                                       \
            const bf16x8 B0 = *(const bf16x8*)(RD);                           \
            const bf16x8 B1 = *(const bf16x8*)((RD) + 32);                    \
            f32x4 a0 = __builtin_amdgcn_mfma_f32_16x16x32_bf16(Ah[0][0], B0, z, 0, 0, 0); \
            f32x4 a1 = __builtin_amdgcn_mfma_f32_16x16x32_bf16(Ah[1][0], B0, z, 0, 0, 0); \
            a0 = __builtin_amdgcn_mfma_f32_16x16x32_bf16(Ah[0][1], B1, a0, 0, 0, 0); \
            a1 = __builtin_amdgcn_mfma_f32_16x16x32_bf16(Ah[1][1], B1, a1, 0, 0, 0); \
            float h0, h1;                                                     \
            GATES(a0, cs0, h0);                                               \
            GATES(a1, cs1, h1);                                               \
            unsigned hpk;                                                     \
            asm("v_cvt_pk_bf16_f32 %0, %1, %2" : "=v"(hpk) : "v"(h0), "v"(h1)); \
            *(WR0) = (unsigned short)(hpk & 0xFFFFu);                         \
            *(WR1) = (unsigned short)(hpk >> 16);                             \
        } else {                                                              \
            const bf16x8 B0 = *(const bf16x8*)(RD);                           \
            const bf16x8 B1 = *(const bf16x8*)((RD) + 32);                    \
            if (lane >= 16 && lane < 32) {                                    \
                const unsigned short hx = bf16_rtne(xa);                      \
                const unsigned short lx = bf16_rtne(xa - bf16_f32(hx));       \
                (XW)[25] = (unsigned)hx | (0x3F80u << 16);                    \
                (XW)[26] = (unsigned)lx | (0x3F80u << 16);                    \
                ((unsigned short*)(XW))[54] = hx;                             \
                xa = xrow[((TI) + 2 < TT) ? (TI) + 2 : TT - 1];               \
            }                                                                 \
            f32x4 a0 = __builtin_amdgcn_mfma_f32_16x16x32_bf16(Ah[0][0], B0, z, 0, 0, 0); \
            a0 = __builtin_amdgcn_mfma_f32_16x16x32_bf16(Ah[0][1], B1, a0, 0, 0, 0); \
            if (lane < 16 && (TI) > 0)                                        \
                yout[(TI) - 1] = a0.x + a0.y + bo;                            \
        }                                                                     \
    } while (0)

    for (int t = 0; t < TT; t += 2) {
        LSTM_STEP(rdA, wrA0, wrA1, xwA, t);        // read plane 0, write plane 1
        asm volatile("s_waitcnt lgkmcnt(0)\n\ts_barrier" ::: "memory");
        LSTM_STEP(rdB, wrB0, wrB1, xwB, t + 1);    // read plane 1, write plane 0
        asm volatile("s_waitcnt lgkmcnt(0)\n\ts_barrier" ::: "memory");
    }
#undef LSTM_STEP
#undef GATES

    // epilogue: y_{TT-1} from plane 0 (h_{511})
    if (wv == NCW) {
        const bf16x8 B0 = *(const bf16x8*)rdA;
        const bf16x8 B1 = *(const bf16x8*)(rdA + 32);
        f32x4 a0 = __builtin_amdgcn_mfma_f32_16x16x32_bf16(Ah[0][0], B0, z, 0, 0, 0);
        a0 = __builtin_amdgcn_mfma_f32_16x16x32_bf16(Ah[0][1], B1, a0, 0, 0, 0);
        if (lane < 16)
            yout[TT - 1] = a0.x + a0.y + bo;
    }
}

extern "C" void kernel_launch(void* const* d_in, const int* in_sizes, int n_in,
                              void* d_out, int out_size, void* d_ws, size_t ws_size,
                              hipStream_t stream) {
    const float* x     = (const float*)d_in[0];
    const float* W_ih  = (const float*)d_in[1];
    const float* W_hh  = (const float*)d_in[2];
    const float* b_ih  = (const float*)d_in[3];
    const float* b_hh  = (const float*)d_in[4];
    const float* W_out = (const float*)d_in[5];
    const float* b_out = (const float*)d_in[6];
    float* out = (float*)d_out;

    const int B = in_sizes[0] / TT;          // 4096
    lstm_mfma17_kernel<<<B / BT, NTH, 0, stream>>>(x, W_ih, W_hh, b_ih, b_hh,
                                                   W_out, b_out, out);
}